// Round 1
// baseline (512.052 us; speedup 1.0000x reference)
//
#include <hip/hip_runtime.h>
#include <math.h>

// Problem constants
#define NPOS 65536   // B*H*W = 8*1*8192
#define NCH  128

// ws layout (float element offsets)
#define OFF_XR   0u                       // xr transposed [n][c]  : 8388608
#define OFF_Y    8388608u                 // y1 / y2 (in-place)    : 8388608
#define OFF_W1T  16777216u                // folded W1^T [cin][cout]
#define OFF_WRT  (OFF_W1T + 16384u)
#define OFF_W2T  (OFF_WRT + 16384u)
#define OFF_W3T  (OFF_W2T + 16384u)
#define OFF_WM   (OFF_W3T + 16384u)       // mask row of cl3_w (128)
#define OFF_B1F  (OFF_WM + 128u)
#define OFF_BRF  (OFF_B1F + 128u)
#define OFF_B2F  (OFF_BRF + 128u)
#define OFF_B3F  (OFF_B2F + 128u)         // 132 (129 used)
#define OFF_INT  (OFF_B3F + 132u)         // int region starts here

__device__ __forceinline__ float lrelu(float v) { return v >= 0.0f ? v : 0.01f * v; }

// ---------------------------------------------------------------------------
// prep: fold BN into conv weights, transpose weights to [cin][cout], zero hist
// ---------------------------------------------------------------------------
__global__ void k_prep(const float* __restrict__ cl1_w, const float* __restrict__ cl1_b,
                       const float* __restrict__ g1, const float* __restrict__ be1,
                       const float* __restrict__ mu1, const float* __restrict__ va1,
                       const float* __restrict__ cl2_w, const float* __restrict__ cl2_b,
                       const float* __restrict__ cl3_w, const float* __restrict__ cl3_b,
                       const float* __restrict__ reg1_w, const float* __restrict__ reg1_b,
                       const float* __restrict__ gr, const float* __restrict__ ber,
                       const float* __restrict__ mur, const float* __restrict__ var_,
                       float* __restrict__ ws_f, int* __restrict__ hist)
{
    int tid = blockIdx.x * 128 + threadIdx.x;   // 16384 threads
    int cin = tid >> 7, cout = tid & 127;
    float s1 = g1[cout] / sqrtf(va1[cout] + 1e-5f);
    float sr = gr[cout] / sqrtf(var_[cout] + 1e-5f);
    ws_f[OFF_W1T + tid] = cl1_w[cout * 128 + cin] * s1;
    ws_f[OFF_WRT + tid] = reg1_w[cout * 128 + cin] * sr;
    ws_f[OFF_W2T + tid] = cl2_w[cout * 128 + cin];
    ws_f[OFF_W3T + tid] = cl3_w[cout * 128 + cin];
    if (tid < 128) {
        float s1b = g1[tid] / sqrtf(va1[tid] + 1e-5f);
        float srb = gr[tid] / sqrtf(var_[tid] + 1e-5f);
        ws_f[OFF_WM  + tid] = cl3_w[128 * 128 + tid];
        ws_f[OFF_B1F + tid] = cl1_b[tid] * s1b + be1[tid] - mu1[tid] * s1b;
        ws_f[OFF_BRF + tid] = reg1_b[tid] * srb + ber[tid] - mur[tid] * srb;
        ws_f[OFF_B2F + tid] = cl2_b[tid];
        hist[tid] = 0;
    }
    if (tid < 129) ws_f[OFF_B3F + tid] = cl3_b[tid];
}

// ---------------------------------------------------------------------------
// GEMM core: tile = 128 couts x 64 positions, 128 threads, 8x8 per thread.
// WT is [cin][cout] (transposed). X row addr = cin*rowStride + base.
// base = nt + b*bmul (bmul=1040384 for x_in layout, 0 for [c][n] ws layout)
// ---------------------------------------------------------------------------
__device__ __forceinline__ void gemm_core(const float* X, const float* __restrict__ WT,
                                          float* w_s, float* x_s,
                                          unsigned base, unsigned rowStride,
                                          float acc[8][8], int t)
{
    const int c0 = (t >> 3) * 8;
    const int p0 = (t & 7) * 8;
    for (int ch = 0; ch < 4; ++ch) {
        #pragma unroll
        for (int l = 0; l < 8; ++l) {                 // stage W chunk 32x128
            int q = t + 128 * l;                      // 1024 float4
            int cin = q >> 5, f4 = (q & 31) << 2;
            *(float4*)&w_s[cin * 128 + f4] =
                *(const float4*)&WT[(unsigned)(ch * 32 + cin) * 128u + f4];
        }
        #pragma unroll
        for (int l = 0; l < 4; ++l) {                 // stage X chunk 32x64
            int q = t + 128 * l;                      // 512 float4
            int cin = q >> 4, f4 = (q & 15) << 2;
            *(float4*)&x_s[cin * 64 + f4] =
                *(const float4*)&X[(unsigned)(ch * 32 + cin) * rowStride + base + f4];
        }
        __syncthreads();
        #pragma unroll 4
        for (int cin = 0; cin < 32; ++cin) {
            const float4 wa = *(const float4*)&w_s[cin * 128 + c0];
            const float4 wb = *(const float4*)&w_s[cin * 128 + c0 + 4];
            const float4 xa = *(const float4*)&x_s[cin * 64 + p0];
            const float4 xb = *(const float4*)&x_s[cin * 64 + p0 + 4];
            const float wv[8] = {wa.x, wa.y, wa.z, wa.w, wb.x, wb.y, wb.z, wb.w};
            const float xv[8] = {xa.x, xa.y, xa.z, xa.w, xb.x, xb.y, xb.z, xb.w};
            #pragma unroll
            for (int i = 0; i < 8; ++i)
                #pragma unroll
                for (int j = 0; j < 8; ++j)
                    acc[i][j] = fmaf(wv[i], xv[j], acc[i][j]);
        }
        __syncthreads();
    }
}

// cl1 (x_in -> Y) and cl2 (Y -> Y in-place). NOTE: no __restrict__ on X/OUT (alias in cl2).
__global__ __launch_bounds__(128, 3)
void k_gemm_lrelu(const float* X, const float* __restrict__ WT,
                  const float* __restrict__ BIAS, float* OUT,
                  unsigned rowStride, unsigned bmul)
{
    __shared__ float w_s[4096];
    __shared__ float x_s[2048];
    int t = threadIdx.x;
    unsigned nt = blockIdx.x * 64u;
    unsigned base = nt + (nt >> 13) * bmul;
    float acc[8][8] = {};
    gemm_core(X, WT, w_s, x_s, base, rowStride, acc, t);
    const int c0 = (t >> 3) * 8;
    const int p0 = (t & 7) * 8;
    #pragma unroll
    for (int i = 0; i < 8; ++i) {
        float b = BIAS[c0 + i];
        float4 o1, o2;
        o1.x = lrelu(acc[i][0] + b); o1.y = lrelu(acc[i][1] + b);
        o1.z = lrelu(acc[i][2] + b); o1.w = lrelu(acc[i][3] + b);
        o2.x = lrelu(acc[i][4] + b); o2.y = lrelu(acc[i][5] + b);
        o2.z = lrelu(acc[i][6] + b); o2.w = lrelu(acc[i][7] + b);
        unsigned ob = (unsigned)(c0 + i) * 65536u + nt + p0;
        *(float4*)&OUT[ob]     = o1;
        *(float4*)&OUT[ob + 4] = o2;
    }
}

// reg1 path: x_in -> XR stored TRANSPOSED [n][c] (position-major) via LDS transpose
__global__ __launch_bounds__(128, 3)
void k_gemm_xr(const float* __restrict__ X, const float* __restrict__ WT,
               const float* __restrict__ BIAS, float* __restrict__ XR,
               unsigned rowStride, unsigned bmul)
{
    __shared__ float smem[8448];                 // max(6144 staging, 64*132 transpose)
    float* w_s = smem;
    float* x_s = smem + 4096;
    int t = threadIdx.x;
    unsigned nt = blockIdx.x * 64u;
    unsigned base = nt + (nt >> 13) * bmul;
    float acc[8][8] = {};
    gemm_core(X, WT, w_s, x_s, base, rowStride, acc, t);
    const int c0 = (t >> 3) * 8;
    const int p0 = (t & 7) * 8;
    // bias+lrelu then scatter into LDS [p][c] (stride 132 to break bank conflicts)
    #pragma unroll
    for (int i = 0; i < 8; ++i) {
        float b = BIAS[c0 + i];
        #pragma unroll
        for (int j = 0; j < 8; ++j)
            smem[(p0 + j) * 132 + c0 + i] = lrelu(acc[i][j] + b);
    }
    __syncthreads();
    int r = t >> 1, half = t & 1;
    unsigned gb = (nt + (unsigned)r) * 128u + half * 64u;
    #pragma unroll
    for (int k = 0; k < 16; ++k)
        *(float4*)&XR[gb + k * 4] = *(float4*)&smem[r * 132 + half * 64 + k * 4];
}

// cl3: Y -> argmax inds + hist, mask channel -> d_out[65536..]
__global__ __launch_bounds__(128, 3)
void k_gemm3(const float* __restrict__ Y, const float* __restrict__ W3T,
             const float* __restrict__ WM, const float* __restrict__ B3,
             float* __restrict__ out_mask, int* __restrict__ inds, int* __restrict__ hist)
{
    __shared__ float w_s[4096];
    __shared__ float x_s[2048];
    __shared__ float wm_s[32];
    __shared__ float lmax[16 * 64];
    __shared__ int   lidx[16 * 64];
    int t = threadIdx.x;
    unsigned nt = blockIdx.x * 64u;
    const int c0 = (t >> 3) * 8;
    const int p0 = (t & 7) * 8;
    const bool domask = (c0 == 120);
    float acc[8][8] = {};
    float macc[8] = {};
    for (int ch = 0; ch < 4; ++ch) {
        #pragma unroll
        for (int l = 0; l < 8; ++l) {
            int q = t + 128 * l;
            int cin = q >> 5, f4 = (q & 31) << 2;
            *(float4*)&w_s[cin * 128 + f4] =
                *(const float4*)&W3T[(unsigned)(ch * 32 + cin) * 128u + f4];
        }
        #pragma unroll
        for (int l = 0; l < 4; ++l) {
            int q = t + 128 * l;
            int cin = q >> 4, f4 = (q & 15) << 2;
            *(float4*)&x_s[cin * 64 + f4] =
                *(const float4*)&Y[(unsigned)(ch * 32 + cin) * 65536u + nt + f4];
        }
        if (t < 32) wm_s[t] = WM[ch * 32 + t];
        __syncthreads();
        #pragma unroll 4
        for (int cin = 0; cin < 32; ++cin) {
            const float4 wa = *(const float4*)&w_s[cin * 128 + c0];
            const float4 wb = *(const float4*)&w_s[cin * 128 + c0 + 4];
            const float4 xa = *(const float4*)&x_s[cin * 64 + p0];
            const float4 xb = *(const float4*)&x_s[cin * 64 + p0 + 4];
            const float wv[8] = {wa.x, wa.y, wa.z, wa.w, wb.x, wb.y, wb.z, wb.w};
            const float xv[8] = {xa.x, xa.y, xa.z, xa.w, xb.x, xb.y, xb.z, xb.w};
            #pragma unroll
            for (int i = 0; i < 8; ++i)
                #pragma unroll
                for (int j = 0; j < 8; ++j)
                    acc[i][j] = fmaf(wv[i], xv[j], acc[i][j]);
            if (domask) {
                float wmv = wm_s[cin];
                #pragma unroll
                for (int j = 0; j < 8; ++j) macc[j] = fmaf(wmv, xv[j], macc[j]);
            }
        }
        __syncthreads();
    }
    // add bias, local argmax over this thread's 8 couts (first-index tie rule)
    float bb[8];
    #pragma unroll
    for (int i = 0; i < 8; ++i) bb[i] = B3[c0 + i];
    #pragma unroll
    for (int j = 0; j < 8; ++j) {
        float m = acc[0][j] + bb[0];
        int id = c0;
        #pragma unroll
        for (int i = 1; i < 8; ++i) {
            float v = acc[i][j] + bb[i];
            if (v > m) { m = v; id = c0 + i; }
        }
        lmax[(c0 >> 3) * 64 + p0 + j] = m;
        lidx[(c0 >> 3) * 64 + p0 + j] = id;
    }
    if (domask) {
        float mb = B3[128];
        #pragma unroll
        for (int j = 0; j < 8; ++j)
            out_mask[nt + p0 + j] = lrelu(macc[j] + mb);
    }
    __syncthreads();
    if (t < 64) {
        int p = t;
        float m = lmax[p];
        int id = lidx[p];
        #pragma unroll
        for (int cg = 1; cg < 16; ++cg) {
            float v = lmax[cg * 64 + p];
            if (v > m) { m = v; id = lidx[cg * 64 + p]; }
        }
        inds[nt + p] = id;
        atomicAdd(&hist[id], 1);
    }
}

// exclusive scan of the 128-bin histogram
__global__ void k_scan(const int* __restrict__ hist, int* __restrict__ off, int* __restrict__ cur)
{
    __shared__ int s[128];
    int t = threadIdx.x;
    int v = hist[t];
    s[t] = v;
    __syncthreads();
    for (int d = 1; d < 128; d <<= 1) {
        int add = (t >= d) ? s[t - d] : 0;
        __syncthreads();
        s[t] += add;
        __syncthreads();
    }
    int excl = s[t] - v;
    off[t] = excl;
    cur[t] = excl;
}

// scatter positions into buckets by argmax index
__global__ void k_scatter(const int* __restrict__ inds, int* __restrict__ cur, int* __restrict__ bucket)
{
    int n = blockIdx.x * 256 + threadIdx.x;
    int id = inds[n];
    int slot = atomicAdd(&cur[id], 1);
    bucket[slot] = n;
}

// bucketed per-position MLP: h = lrelu(xr*W2[k]+b2[k]); reg = h*w3[k]+b3[k]
// grid (16 chunks, 128 buckets), 256 threads, 64 positions/tile, 8 outs/thread
__global__ __launch_bounds__(256, 4)
void k_reg(const float* __restrict__ XR, const float* __restrict__ cm2w,
           const float* __restrict__ cm2b, const float* __restrict__ cm3w,
           const float* __restrict__ cm3b, const int* __restrict__ hist,
           const int* __restrict__ off, const int* __restrict__ bucket,
           float* __restrict__ out)
{
    int k = blockIdx.y;
    int cnt = hist[k];
    if (cnt == 0) return;
    int base = off[k];
    __shared__ float wk[4096];        // cm2_w[k]: [128][32]
    __shared__ float xP[64 * 132];    // gathered xr rows [p][i]
    int t = threadIdx.x;
    #pragma unroll
    for (int l = 0; l < 4; ++l) {     // stage W once
        int q = t + 256 * l;          // 1024 float4
        int i = q >> 3, o4 = (q & 7) << 2;
        *(float4*)&wk[i * 32 + o4] =
            *(const float4*)&cm2w[(unsigned)k * 4096u + i * 32 + o4];
    }
    int og = t & 3, pg = t >> 2;
    int o0 = og * 8;
    float cbv[8], w3v[8];
    #pragma unroll
    for (int o = 0; o < 8; ++o) {
        cbv[o] = cm2b[k * 32 + o0 + o];
        w3v[o] = cm3w[k * 32 + o0 + o];
    }
    float c3b = cm3b[k];
    for (int start = blockIdx.x * 64; start < cnt; start += 16 * 64) {
        __syncthreads();
        {   // gather 64 xr rows -> LDS (transposed-free: [p][i], pad 132)
            int p = t >> 2, seg = t & 3;
            int sidx = start + p;
            if (sidx >= cnt) sidx = cnt - 1;
            int n = bucket[base + sidx];
            #pragma unroll
            for (int q4 = 0; q4 < 8; ++q4)
                *(float4*)&xP[p * 132 + seg * 32 + q4 * 4] =
                    *(const float4*)&XR[(unsigned)n * 128u + seg * 32 + q4 * 4];
        }
        __syncthreads();
        float h[8] = {};
        #pragma unroll 4
        for (int i = 0; i < 128; ++i) {
            float xv = xP[pg * 132 + i];
            const float4 wa = *(const float4*)&wk[i * 32 + o0];
            const float4 wb = *(const float4*)&wk[i * 32 + o0 + 4];
            h[0] = fmaf(wa.x, xv, h[0]); h[1] = fmaf(wa.y, xv, h[1]);
            h[2] = fmaf(wa.z, xv, h[2]); h[3] = fmaf(wa.w, xv, h[3]);
            h[4] = fmaf(wb.x, xv, h[4]); h[5] = fmaf(wb.y, xv, h[5]);
            h[6] = fmaf(wb.z, xv, h[6]); h[7] = fmaf(wb.w, xv, h[7]);
        }
        float partial = 0.0f;
        #pragma unroll
        for (int o = 0; o < 8; ++o) {
            float v = lrelu(h[o] + cbv[o]);
            partial = fmaf(v, w3v[o], partial);
        }
        partial += __shfl_xor(partial, 1);
        partial += __shfl_xor(partial, 2);
        if (og == 0 && start + pg < cnt) {
            int n = bucket[base + start + pg];
            out[n] = ((float)k + partial + c3b) * (1.0f / 128.0f);
        }
    }
}

extern "C" void kernel_launch(void* const* d_in, const int* in_sizes, int n_in,
                              void* d_out, int out_size, void* d_ws, size_t ws_size,
                              hipStream_t stream)
{
    (void)in_sizes; (void)n_in; (void)out_size; (void)ws_size;
    const float* x_in   = (const float*)d_in[0];
    const float* cl1_w  = (const float*)d_in[1];
    const float* cl1_b  = (const float*)d_in[2];
    const float* g1     = (const float*)d_in[3];
    const float* be1    = (const float*)d_in[4];
    const float* mu1    = (const float*)d_in[5];
    const float* va1    = (const float*)d_in[6];
    const float* cl2_w  = (const float*)d_in[7];
    const float* cl2_b  = (const float*)d_in[8];
    const float* cl3_w  = (const float*)d_in[9];
    const float* cl3_b  = (const float*)d_in[10];
    const float* reg1_w = (const float*)d_in[11];
    const float* reg1_b = (const float*)d_in[12];
    const float* gr     = (const float*)d_in[13];
    const float* ber    = (const float*)d_in[14];
    const float* mur    = (const float*)d_in[15];
    const float* var_   = (const float*)d_in[16];
    const float* cm2w   = (const float*)d_in[17];
    const float* cm2b   = (const float*)d_in[18];
    const float* cm3w   = (const float*)d_in[19];
    const float* cm3b   = (const float*)d_in[20];

    float* ws_f = (float*)d_ws;
    float* XR  = ws_f + OFF_XR;
    float* Y   = ws_f + OFF_Y;
    int*   wsi    = (int*)(ws_f + OFF_INT);
    int*   inds   = wsi;
    int*   hist   = wsi + 65536;
    int*   offb   = hist + 128;
    int*   cur    = offb + 128;
    int*   bucket = cur + 128;
    float* out = (float*)d_out;

    hipLaunchKernelGGL(k_prep, dim3(128), dim3(128), 0, stream,
                       cl1_w, cl1_b, g1, be1, mu1, va1, cl2_w, cl2_b, cl3_w, cl3_b,
                       reg1_w, reg1_b, gr, ber, mur, var_, ws_f, hist);
    // cl1: x_in -> Y (y1)
    hipLaunchKernelGGL(k_gemm_lrelu, dim3(1024), dim3(128), 0, stream,
                       x_in, ws_f + OFF_W1T, ws_f + OFF_B1F, Y, 8192u, 1040384u);
    // reg1: x_in -> XR (transposed [n][c])
    hipLaunchKernelGGL(k_gemm_xr, dim3(1024), dim3(128), 0, stream,
                       x_in, ws_f + OFF_WRT, ws_f + OFF_BRF, XR, 8192u, 1040384u);
    // cl2: Y -> Y (in-place)
    hipLaunchKernelGGL(k_gemm_lrelu, dim3(1024), dim3(128), 0, stream,
                       Y, ws_f + OFF_W2T, ws_f + OFF_B2F, Y, 65536u, 0u);
    // cl3 + argmax + mask
    hipLaunchKernelGGL(k_gemm3, dim3(1024), dim3(128), 0, stream,
                       Y, ws_f + OFF_W3T, ws_f + OFF_WM, ws_f + OFF_B3F,
                       out + 65536, inds, hist);
    hipLaunchKernelGGL(k_scan, dim3(1), dim3(128), 0, stream, hist, offb, cur);
    hipLaunchKernelGGL(k_scatter, dim3(256), dim3(256), 0, stream, inds, cur, bucket);
    hipLaunchKernelGGL(k_reg, dim3(16, 128), dim3(256), 0, stream,
                       XR, cm2w, cm2b, cm3w, cm3b, hist, offb, bucket, out);
}

// Round 2
// 459.972 us; speedup vs baseline: 1.1132x; 1.1132x over previous
//
#include <hip/hip_runtime.h>
#include <math.h>

// Problem constants
#define NPOS 65536   // B*H*W = 8*1*8192
#define NCH  128

// ws layout (float element offsets)
#define OFF_XR   0u                       // xr transposed [n][c]  : 8388608 floats
#define OFF_W1T  8388608u                 // folded W1^T [cin][cout]
#define OFF_WRT  (OFF_W1T + 16384u)
#define OFF_W2T  (OFF_WRT + 16384u)
#define OFF_W3T  (OFF_W2T + 16384u)
#define OFF_WM   (OFF_W3T + 16384u)       // mask row of cl3_w (128)
#define OFF_B1F  (OFF_WM + 128u)
#define OFF_BRF  (OFF_B1F + 128u)
#define OFF_B2F  (OFF_BRF + 128u)
#define OFF_B3F  (OFF_B2F + 128u)         // 132 (129 used)
#define OFF_INT  (OFF_B3F + 132u)         // int region starts here

__device__ __forceinline__ float lrelu(float v) { return v >= 0.0f ? v : 0.01f * v; }

// ---------------------------------------------------------------------------
// prep: fold BN into conv weights, transpose weights to [cin][cout], zero hist
// ---------------------------------------------------------------------------
__global__ void k_prep(const float* __restrict__ cl1_w, const float* __restrict__ cl1_b,
                       const float* __restrict__ g1, const float* __restrict__ be1,
                       const float* __restrict__ mu1, const float* __restrict__ va1,
                       const float* __restrict__ cl2_w, const float* __restrict__ cl2_b,
                       const float* __restrict__ cl3_w, const float* __restrict__ cl3_b,
                       const float* __restrict__ reg1_w, const float* __restrict__ reg1_b,
                       const float* __restrict__ gr, const float* __restrict__ ber,
                       const float* __restrict__ mur, const float* __restrict__ var_,
                       float* __restrict__ ws_f, int* __restrict__ hist)
{
    int tid = blockIdx.x * 128 + threadIdx.x;   // 16384 threads
    int cin = tid >> 7, cout = tid & 127;
    float s1 = g1[cout] / sqrtf(va1[cout] + 1e-5f);
    float sr = gr[cout] / sqrtf(var_[cout] + 1e-5f);
    ws_f[OFF_W1T + tid] = cl1_w[cout * 128 + cin] * s1;
    ws_f[OFF_WRT + tid] = reg1_w[cout * 128 + cin] * sr;
    ws_f[OFF_W2T + tid] = cl2_w[cout * 128 + cin];
    ws_f[OFF_W3T + tid] = cl3_w[cout * 128 + cin];
    if (tid < 128) {
        float s1b = g1[tid] / sqrtf(va1[tid] + 1e-5f);
        float srb = gr[tid] / sqrtf(var_[tid] + 1e-5f);
        ws_f[OFF_WM  + tid] = cl3_w[128 * 128 + tid];
        ws_f[OFF_B1F + tid] = cl1_b[tid] * s1b + be1[tid] - mu1[tid] * s1b;
        ws_f[OFF_BRF + tid] = reg1_b[tid] * srb + ber[tid] - mur[tid] * srb;
        ws_f[OFF_B2F + tid] = cl2_b[tid];
        hist[tid] = 0;
    }
    if (tid < 129) ws_f[OFF_B3F + tid] = cl3_b[tid];
}

// ---------------------------------------------------------------------------
// FUSED pipeline: block owns 64 positions x all 128 channels.
//   stage x tile (128cin x 64pos) in LDS
//   P1: y1 = lrelu(BN(W1 x)), xr = lrelu(BN(Wr x))  [shared x operand]
//       xr -> global (position-major), y1 overwrites x tile in LDS
//   P2: y2 = lrelu(W2 y1 + b2)  -> overwrites LDS tile
//   P3: y3 = W3 y2 + b3 (+ mask row), argmax over 128, hist atomic, mask out
// 256 threads, thread tile = 4 couts x 8 pos.
// LDS: XA 32KB + Wb0 16KB + Wb1 16KB = 64KB -> 2 blocks/CU, 8 waves/CU.
// ---------------------------------------------------------------------------
__global__ __launch_bounds__(256, 2)
void k_fused(const float* __restrict__ X, const float* __restrict__ wsf,
             float* __restrict__ XR, float* __restrict__ out_mask,
             int* __restrict__ inds, int* __restrict__ hist)
{
    __shared__ float XA[128 * 64];     // x tile, then y1, then y2
    __shared__ float Wb0[32 * 128];    // W chunk (also lmax scratch)
    __shared__ float Wb1[32 * 128];    // W chunk (also lidx scratch)
    __shared__ float swm[32];

    const int t = threadIdx.x;
    const unsigned nt = blockIdx.x * 64u;
    const unsigned base = nt + (nt >> 13) * 1040384u;   // b*1048576 + w0
    const int g  = t >> 3;          // 0..31 cout-group
    const int c0 = g * 4;
    const int p0 = (t & 7) * 8;

    const float* W1T = wsf + OFF_W1T;
    const float* WRT = wsf + OFF_WRT;
    const float* W2T = wsf + OFF_W2T;
    const float* W3T = wsf + OFF_W3T;
    const float* WM  = wsf + OFF_WM;
    const float* b1f = wsf + OFF_B1F;
    const float* brf = wsf + OFF_BRF;
    const float* b2f = wsf + OFF_B2F;
    const float* b3f = wsf + OFF_B3F;

    // ---- stage x tile: 128 rows x 64 floats ----
    #pragma unroll
    for (int l = 0; l < 8; ++l) {
        int q = t + 256 * l;                    // 2048 float4
        int row = q >> 4, f4 = (q & 15) << 2;
        *(float4*)&XA[row * 64 + f4] =
            *(const float4*)&X[(unsigned)row * 8192u + base + f4];
    }

    // ---- P1: y1 and xr together (shared x fragments) ----
    float aY[4][8] = {};
    float aR[4][8] = {};
    for (int ch = 0; ch < 4; ++ch) {
        #pragma unroll
        for (int l = 0; l < 4; ++l) {
            int q = t + 256 * l;                // 1024 float4 each
            int ci = q >> 5, f4 = (q & 31) << 2;
            *(float4*)&Wb0[ci * 128 + f4] =
                *(const float4*)&W1T[(unsigned)(ch * 32 + ci) * 128u + f4];
            *(float4*)&Wb1[ci * 128 + f4] =
                *(const float4*)&WRT[(unsigned)(ch * 32 + ci) * 128u + f4];
        }
        __syncthreads();
        #pragma unroll 2
        for (int ci = 0; ci < 32; ++ci) {
            const int cin = ch * 32 + ci;
            const float4 w1 = *(const float4*)&Wb0[ci * 128 + c0];
            const float4 wr = *(const float4*)&Wb1[ci * 128 + c0];
            const float4 xa = *(const float4*)&XA[cin * 64 + p0];
            const float4 xb = *(const float4*)&XA[cin * 64 + p0 + 4];
            const float xv[8]  = {xa.x, xa.y, xa.z, xa.w, xb.x, xb.y, xb.z, xb.w};
            const float w1v[4] = {w1.x, w1.y, w1.z, w1.w};
            const float wrv[4] = {wr.x, wr.y, wr.z, wr.w};
            #pragma unroll
            for (int i = 0; i < 4; ++i)
                #pragma unroll
                for (int j = 0; j < 8; ++j) {
                    aY[i][j] = fmaf(w1v[i], xv[j], aY[i][j]);
                    aR[i][j] = fmaf(wrv[i], xv[j], aR[i][j]);
                }
        }
        __syncthreads();   // protect Wb0/Wb1 restage; last iter: protects XA overwrite
    }

    // xr: bias + lrelu -> global [n][c] straight from regs
    {
        const float4 bq = *(const float4*)&brf[c0];
        const float bv[4] = {bq.x, bq.y, bq.z, bq.w};
        #pragma unroll
        for (int j = 0; j < 8; ++j) {
            float4 o;
            o.x = lrelu(aR[0][j] + bv[0]);
            o.y = lrelu(aR[1][j] + bv[1]);
            o.z = lrelu(aR[2][j] + bv[2]);
            o.w = lrelu(aR[3][j] + bv[3]);
            *(float4*)&XR[(unsigned)(nt + p0 + j) * 128u + c0] = o;
        }
    }
    // y1 -> overwrite XA (all XA reads finished at last barrier)
    {
        const float4 bq = *(const float4*)&b1f[c0];
        const float bv[4] = {bq.x, bq.y, bq.z, bq.w};
        #pragma unroll
        for (int i = 0; i < 4; ++i) {
            float4 o1, o2;
            o1.x = lrelu(aY[i][0] + bv[i]); o1.y = lrelu(aY[i][1] + bv[i]);
            o1.z = lrelu(aY[i][2] + bv[i]); o1.w = lrelu(aY[i][3] + bv[i]);
            o2.x = lrelu(aY[i][4] + bv[i]); o2.y = lrelu(aY[i][5] + bv[i]);
            o2.z = lrelu(aY[i][6] + bv[i]); o2.w = lrelu(aY[i][7] + bv[i]);
            *(float4*)&XA[(c0 + i) * 64 + p0]     = o1;
            *(float4*)&XA[(c0 + i) * 64 + p0 + 4] = o2;
        }
    }
    __syncthreads();

    // ---- P2: y2 = lrelu(W2 y1 + b2) ----
    float aZ[4][8] = {};
    for (int ch = 0; ch < 4; ++ch) {
        #pragma unroll
        for (int l = 0; l < 4; ++l) {
            int q = t + 256 * l;
            int ci = q >> 5, f4 = (q & 31) << 2;
            *(float4*)&Wb0[ci * 128 + f4] =
                *(const float4*)&W2T[(unsigned)(ch * 32 + ci) * 128u + f4];
        }
        __syncthreads();
        #pragma unroll 4
        for (int ci = 0; ci < 32; ++ci) {
            const int cin = ch * 32 + ci;
            const float4 w2 = *(const float4*)&Wb0[ci * 128 + c0];
            const float4 xa = *(const float4*)&XA[cin * 64 + p0];
            const float4 xb = *(const float4*)&XA[cin * 64 + p0 + 4];
            const float xv[8]  = {xa.x, xa.y, xa.z, xa.w, xb.x, xb.y, xb.z, xb.w};
            const float wv[4]  = {w2.x, w2.y, w2.z, w2.w};
            #pragma unroll
            for (int i = 0; i < 4; ++i)
                #pragma unroll
                for (int j = 0; j < 8; ++j)
                    aZ[i][j] = fmaf(wv[i], xv[j], aZ[i][j]);
        }
        __syncthreads();
    }
    // y2 -> overwrite XA
    {
        const float4 bq = *(const float4*)&b2f[c0];
        const float bv[4] = {bq.x, bq.y, bq.z, bq.w};
        #pragma unroll
        for (int i = 0; i < 4; ++i) {
            float4 o1, o2;
            o1.x = lrelu(aZ[i][0] + bv[i]); o1.y = lrelu(aZ[i][1] + bv[i]);
            o1.z = lrelu(aZ[i][2] + bv[i]); o1.w = lrelu(aZ[i][3] + bv[i]);
            o2.x = lrelu(aZ[i][4] + bv[i]); o2.y = lrelu(aZ[i][5] + bv[i]);
            o2.z = lrelu(aZ[i][6] + bv[i]); o2.w = lrelu(aZ[i][7] + bv[i]);
            *(float4*)&XA[(c0 + i) * 64 + p0]     = o1;
            *(float4*)&XA[(c0 + i) * 64 + p0 + 4] = o2;
        }
    }
    __syncthreads();

    // ---- P3: logits + mask ----
    float aL[4][8] = {};
    float am[8] = {};
    const bool domask = (g == 31);
    for (int ch = 0; ch < 4; ++ch) {
        #pragma unroll
        for (int l = 0; l < 4; ++l) {
            int q = t + 256 * l;
            int ci = q >> 5, f4 = (q & 31) << 2;
            *(float4*)&Wb0[ci * 128 + f4] =
                *(const float4*)&W3T[(unsigned)(ch * 32 + ci) * 128u + f4];
        }
        if (t < 32) swm[t] = WM[ch * 32 + t];
        __syncthreads();
        #pragma unroll 4
        for (int ci = 0; ci < 32; ++ci) {
            const int cin = ch * 32 + ci;
            const float4 w3 = *(const float4*)&Wb0[ci * 128 + c0];
            const float4 xa = *(const float4*)&XA[cin * 64 + p0];
            const float4 xb = *(const float4*)&XA[cin * 64 + p0 + 4];
            const float xv[8]  = {xa.x, xa.y, xa.z, xa.w, xb.x, xb.y, xb.z, xb.w};
            const float wv[4]  = {w3.x, w3.y, w3.z, w3.w};
            #pragma unroll
            for (int i = 0; i < 4; ++i)
                #pragma unroll
                for (int j = 0; j < 8; ++j)
                    aL[i][j] = fmaf(wv[i], xv[j], aL[i][j]);
            if (domask) {
                const float wmv = swm[ci];
                #pragma unroll
                for (int j = 0; j < 8; ++j) am[j] = fmaf(wmv, xv[j], am[j]);
            }
        }
        __syncthreads();
    }

    // per-thread argmax over its 4 couts (strict >, ascending index = numpy tie rule)
    float* lmax = Wb0;          // 32*64 floats
    int*   lidx = (int*)Wb1;
    {
        const float4 bq = *(const float4*)&b3f[c0];
        const float bv[4] = {bq.x, bq.y, bq.z, bq.w};
        #pragma unroll
        for (int j = 0; j < 8; ++j) {
            float m = aL[0][j] + bv[0];
            int id = c0;
            #pragma unroll
            for (int i = 1; i < 4; ++i) {
                float v = aL[i][j] + bv[i];
                if (v > m) { m = v; id = c0 + i; }
            }
            lmax[g * 64 + p0 + j] = m;
            lidx[g * 64 + p0 + j] = id;
        }
    }
    if (domask) {
        const float mb = b3f[128];
        #pragma unroll
        for (int j = 0; j < 8; ++j)
            out_mask[nt + p0 + j] = lrelu(am[j] + mb);
    }
    __syncthreads();
    if (t < 64) {
        float m = lmax[t];
        int id = lidx[t];
        #pragma unroll
        for (int cg = 1; cg < 32; ++cg) {
            float v = lmax[cg * 64 + t];
            if (v > m) { m = v; id = lidx[cg * 64 + t]; }
        }
        inds[nt + t] = id;
        atomicAdd(&hist[id], 1);
    }
}

// exclusive scan of the 128-bin histogram
__global__ void k_scan(const int* __restrict__ hist, int* __restrict__ off, int* __restrict__ cur)
{
    __shared__ int s[128];
    int t = threadIdx.x;
    int v = hist[t];
    s[t] = v;
    __syncthreads();
    for (int d = 1; d < 128; d <<= 1) {
        int add = (t >= d) ? s[t - d] : 0;
        __syncthreads();
        s[t] += add;
        __syncthreads();
    }
    int excl = s[t] - v;
    off[t] = excl;
    cur[t] = excl;
}

// scatter positions into buckets by argmax index
__global__ void k_scatter(const int* __restrict__ inds, int* __restrict__ cur, int* __restrict__ bucket)
{
    int n = blockIdx.x * 256 + threadIdx.x;
    int id = inds[n];
    int slot = atomicAdd(&cur[id], 1);
    bucket[slot] = n;
}

// bucketed per-position MLP: h = lrelu(xr*W2[k]+b2[k]); reg = h*w3[k]+b3[k]
// grid (16 chunks, 128 buckets), 256 threads, 64 positions/tile, 8 outs/thread
__global__ __launch_bounds__(256, 4)
void k_reg(const float* __restrict__ XR, const float* __restrict__ cm2w,
           const float* __restrict__ cm2b, const float* __restrict__ cm3w,
           const float* __restrict__ cm3b, const int* __restrict__ hist,
           const int* __restrict__ off, const int* __restrict__ bucket,
           float* __restrict__ out)
{
    int k = blockIdx.y;
    int cnt = hist[k];
    if (cnt == 0) return;
    if ((int)(blockIdx.x * 64) >= cnt) return;   // uniform early-exit for tail blocks
    int base = off[k];
    __shared__ float wk[4096];        // cm2_w[k]: [128][32]
    __shared__ float xP[64 * 132];    // gathered xr rows [p][i]
    int t = threadIdx.x;
    #pragma unroll
    for (int l = 0; l < 4; ++l) {     // stage W once
        int q = t + 256 * l;          // 1024 float4
        int i = q >> 3, o4 = (q & 7) << 2;
        *(float4*)&wk[i * 32 + o4] =
            *(const float4*)&cm2w[(unsigned)k * 4096u + i * 32 + o4];
    }
    int og = t & 3, pg = t >> 2;
    int o0 = og * 8;
    float cbv[8], w3v[8];
    #pragma unroll
    for (int o = 0; o < 8; ++o) {
        cbv[o] = cm2b[k * 32 + o0 + o];
        w3v[o] = cm3w[k * 32 + o0 + o];
    }
    float c3b = cm3b[k];
    for (int start = blockIdx.x * 64; start < cnt; start += 16 * 64) {
        __syncthreads();
        {   // gather 64 xr rows -> LDS ([p][i], pad 132)
            int p = t >> 2, seg = t & 3;
            int sidx = start + p;
            if (sidx >= cnt) sidx = cnt - 1;
            int n = bucket[base + sidx];
            #pragma unroll
            for (int q4 = 0; q4 < 8; ++q4)
                *(float4*)&xP[p * 132 + seg * 32 + q4 * 4] =
                    *(const float4*)&XR[(unsigned)n * 128u + seg * 32 + q4 * 4];
        }
        __syncthreads();
        float h[8] = {};
        #pragma unroll 4
        for (int i = 0; i < 128; ++i) {
            float xv = xP[pg * 132 + i];
            const float4 wa = *(const float4*)&wk[i * 32 + o0];
            const float4 wb = *(const float4*)&wk[i * 32 + o0 + 4];
            h[0] = fmaf(wa.x, xv, h[0]); h[1] = fmaf(wa.y, xv, h[1]);
            h[2] = fmaf(wa.z, xv, h[2]); h[3] = fmaf(wa.w, xv, h[3]);
            h[4] = fmaf(wb.x, xv, h[4]); h[5] = fmaf(wb.y, xv, h[5]);
            h[6] = fmaf(wb.z, xv, h[6]); h[7] = fmaf(wb.w, xv, h[7]);
        }
        float partial = 0.0f;
        #pragma unroll
        for (int o = 0; o < 8; ++o) {
            float v = lrelu(h[o] + cbv[o]);
            partial = fmaf(v, w3v[o], partial);
        }
        partial += __shfl_xor(partial, 1);
        partial += __shfl_xor(partial, 2);
        if (og == 0 && start + pg < cnt) {
            int n = bucket[base + start + pg];
            out[n] = ((float)k + partial + c3b) * (1.0f / 128.0f);
        }
    }
}

extern "C" void kernel_launch(void* const* d_in, const int* in_sizes, int n_in,
                              void* d_out, int out_size, void* d_ws, size_t ws_size,
                              hipStream_t stream)
{
    (void)in_sizes; (void)n_in; (void)out_size; (void)ws_size;
    const float* x_in   = (const float*)d_in[0];
    const float* cl1_w  = (const float*)d_in[1];
    const float* cl1_b  = (const float*)d_in[2];
    const float* g1     = (const float*)d_in[3];
    const float* be1    = (const float*)d_in[4];
    const float* mu1    = (const float*)d_in[5];
    const float* va1    = (const float*)d_in[6];
    const float* cl2_w  = (const float*)d_in[7];
    const float* cl2_b  = (const float*)d_in[8];
    const float* cl3_w  = (const float*)d_in[9];
    const float* cl3_b  = (const float*)d_in[10];
    const float* reg1_w = (const float*)d_in[11];
    const float* reg1_b = (const float*)d_in[12];
    const float* gr     = (const float*)d_in[13];
    const float* ber    = (const float*)d_in[14];
    const float* mur    = (const float*)d_in[15];
    const float* var_   = (const float*)d_in[16];
    const float* cm2w   = (const float*)d_in[17];
    const float* cm2b   = (const float*)d_in[18];
    const float* cm3w   = (const float*)d_in[19];
    const float* cm3b   = (const float*)d_in[20];

    float* ws_f = (float*)d_ws;
    float* XR   = ws_f + OFF_XR;
    int*   wsi    = (int*)(ws_f + OFF_INT);
    int*   inds   = wsi;
    int*   hist   = wsi + 65536;
    int*   offb   = hist + 128;
    int*   cur    = offb + 128;
    int*   bucket = cur + 128;
    float* out = (float*)d_out;

    hipLaunchKernelGGL(k_prep, dim3(128), dim3(128), 0, stream,
                       cl1_w, cl1_b, g1, be1, mu1, va1, cl2_w, cl2_b, cl3_w, cl3_b,
                       reg1_w, reg1_b, gr, ber, mur, var_, ws_f, hist);
    hipLaunchKernelGGL(k_fused, dim3(1024), dim3(256), 0, stream,
                       x_in, ws_f, XR, out + 65536, inds, hist);
    hipLaunchKernelGGL(k_scan, dim3(1), dim3(128), 0, stream, hist, offb, cur);
    hipLaunchKernelGGL(k_scatter, dim3(256), dim3(256), 0, stream, inds, cur, bucket);
    hipLaunchKernelGGL(k_reg, dim3(16, 128), dim3(256), 0, stream,
                       XR, cm2w, cm2b, cm3w, cm3b, hist, offb, bucket, out);
}

// Round 4
// 370.132 us; speedup vs baseline: 1.3834x; 1.2427x over previous
//
#include <hip/hip_runtime.h>
#include <math.h>

// Problem constants
#define NPOS 65536   // B*H*W = 8*1*8192
#define NCH  128

// ws layout (float element offsets)
#define OFF_XR   0u                       // xr transposed [n][c]  : 8388608 floats
#define OFF_W1T  8388608u                 // folded W1^T [cin][cout]
#define OFF_WRT  (OFF_W1T + 16384u)
#define OFF_W2T  (OFF_WRT + 16384u)
#define OFF_W3T  (OFF_W2T + 16384u)
#define OFF_WM   (OFF_W3T + 16384u)       // mask row of cl3_w (128)
#define OFF_B1F  (OFF_WM + 128u)
#define OFF_BRF  (OFF_B1F + 128u)
#define OFF_B2F  (OFF_BRF + 128u)
#define OFF_B3F  (OFF_B2F + 128u)         // 132 (129 used)
#define OFF_INT  (OFF_B3F + 132u)         // int region starts here

__device__ __forceinline__ float lrelu(float v) { return v >= 0.0f ? v : 0.01f * v; }

// ---------------------------------------------------------------------------
// prep: fold BN into conv weights, transpose weights to [cin][cout], zero hist
// ---------------------------------------------------------------------------
__global__ void k_prep(const float* __restrict__ cl1_w, const float* __restrict__ cl1_b,
                       const float* __restrict__ g1, const float* __restrict__ be1,
                       const float* __restrict__ mu1, const float* __restrict__ va1,
                       const float* __restrict__ cl2_w, const float* __restrict__ cl2_b,
                       const float* __restrict__ cl3_w, const float* __restrict__ cl3_b,
                       const float* __restrict__ reg1_w, const float* __restrict__ reg1_b,
                       const float* __restrict__ gr, const float* __restrict__ ber,
                       const float* __restrict__ mur, const float* __restrict__ var_,
                       float* __restrict__ ws_f, int* __restrict__ hist)
{
    int tid = blockIdx.x * 128 + threadIdx.x;   // 16384 threads
    int cin = tid >> 7, cout = tid & 127;
    float s1 = g1[cout] / sqrtf(va1[cout] + 1e-5f);
    float sr = gr[cout] / sqrtf(var_[cout] + 1e-5f);
    ws_f[OFF_W1T + tid] = cl1_w[cout * 128 + cin] * s1;
    ws_f[OFF_WRT + tid] = reg1_w[cout * 128 + cin] * sr;
    ws_f[OFF_W2T + tid] = cl2_w[cout * 128 + cin];
    ws_f[OFF_W3T + tid] = cl3_w[cout * 128 + cin];
    if (tid < 128) {
        float s1b = g1[tid] / sqrtf(va1[tid] + 1e-5f);
        float srb = gr[tid] / sqrtf(var_[tid] + 1e-5f);
        ws_f[OFF_WM  + tid] = cl3_w[128 * 128 + tid];
        ws_f[OFF_B1F + tid] = cl1_b[tid] * s1b + be1[tid] - mu1[tid] * s1b;
        ws_f[OFF_BRF + tid] = reg1_b[tid] * srb + ber[tid] - mur[tid] * srb;
        ws_f[OFF_B2F + tid] = cl2_b[tid];
        hist[tid] = 0;
    }
    if (tid < 129) ws_f[OFF_B3F + tid] = cl3_b[tid];
}

// ---------------------------------------------------------------------------
// FUSED pipeline, scalar-weight version.
// Block = 256 thr = 4 waves; tile = 64 positions (lanes) x 128 couts.
// Wave wv owns couts [wv*32, wv*32+32): weights read via wave-uniform s_load
// (L2/K$-cached) -> ZERO LDS for weights, 1 ds_read_b32 per cin for x.
// LDS: XA [128][68] = 34.8 KB -> 4 blocks/CU, 16 waves/CU, VALU-bound.
// ---------------------------------------------------------------------------
__global__ __launch_bounds__(256, 4)
void k_fused(const float* __restrict__ X, const float* __restrict__ wsf,
             float* __restrict__ XR, float* __restrict__ out_mask,
             int* __restrict__ inds, int* __restrict__ hist)
{
    __shared__ float XA[128 * 68];     // x tile, then y1, then y2 ([cin][pos], pad 68)
    __shared__ float rmax[4 * 68];
    __shared__ int   ridx[4 * 68];

    const int t = threadIdx.x;
    const int lane = t & 63;
    const int wv = __builtin_amdgcn_readfirstlane(t >> 6);   // wave-uniform SGPR
    const unsigned nt = blockIdx.x * 64u;
    const unsigned base = nt + (nt >> 13) * 1040384u;        // b*1048576 + w0

    const float* W1T = wsf + OFF_W1T + wv * 32;   // [cin][128] rows, our 32-seg
    const float* WRT = wsf + OFF_WRT + wv * 32;
    const float* W2T = wsf + OFF_W2T + wv * 32;
    const float* W3T = wsf + OFF_W3T + wv * 32;
    const float* WM  = wsf + OFF_WM;
    const float* b1f = wsf + OFF_B1F + wv * 32;
    const float* brf = wsf + OFF_BRF + wv * 32;
    const float* b2f = wsf + OFF_B2F + wv * 32;
    const float* b3f = wsf + OFF_B3F;

    // ---- stage x tile: 128 rows x 64 floats -> XA[row][68] ----
    // 128 rows x 16 float4/row = 2048 float4 over 256 threads -> 8 iters
    #pragma unroll
    for (int l = 0; l < 8; ++l) {
        int q = t + 256 * l;                    // 0..2047
        int row = q >> 4, c4 = (q & 15) << 2;
        *(float4*)&XA[row * 68 + c4] =
            *(const float4*)&X[(unsigned)row * 8192u + base + c4];
    }
    __syncthreads();

    // ---- P1: y1 and xr together (shared x reads, dual accumulators) ----
    float aY[32] = {};
    float aR[32] = {};
    for (int ci = 0; ci < 128; ++ci) {
        const float xv = XA[ci * 68 + lane];
        const float* w1r = W1T + (unsigned)ci * 128u;   // uniform -> s_load
        const float* wrr = WRT + (unsigned)ci * 128u;
        #pragma unroll
        for (int c = 0; c < 32; ++c) {
            aY[c] = fmaf(w1r[c], xv, aY[c]);
            aR[c] = fmaf(wrr[c], xv, aR[c]);
        }
    }
    // xr: bias + lrelu -> global [n][c] straight from regs
    {
        const unsigned xrb = (nt + (unsigned)lane) * 128u + (unsigned)(wv * 32);
        #pragma unroll
        for (int c4 = 0; c4 < 8; ++c4) {
            float4 o;
            o.x = lrelu(aR[c4 * 4 + 0] + brf[c4 * 4 + 0]);
            o.y = lrelu(aR[c4 * 4 + 1] + brf[c4 * 4 + 1]);
            o.z = lrelu(aR[c4 * 4 + 2] + brf[c4 * 4 + 2]);
            o.w = lrelu(aR[c4 * 4 + 3] + brf[c4 * 4 + 3]);
            *(float4*)&XR[xrb + c4 * 4] = o;
        }
    }
    __syncthreads();                      // all P1 XA reads done
    #pragma unroll
    for (int c = 0; c < 32; ++c)
        XA[(wv * 32 + c) * 68 + lane] = lrelu(aY[c] + b1f[c]);
    __syncthreads();

    // ---- P2: y2 = lrelu(W2 y1 + b2) ----
    float aZ[32] = {};
    for (int ci = 0; ci < 128; ++ci) {
        const float xv = XA[ci * 68 + lane];
        const float* w2r = W2T + (unsigned)ci * 128u;
        #pragma unroll
        for (int c = 0; c < 32; ++c)
            aZ[c] = fmaf(w2r[c], xv, aZ[c]);
    }
    __syncthreads();
    #pragma unroll
    for (int c = 0; c < 32; ++c)
        XA[(wv * 32 + c) * 68 + lane] = lrelu(aZ[c] + b2f[c]);
    __syncthreads();

    // ---- P3: logits ----
    float aL[32] = {};
    for (int ci = 0; ci < 128; ++ci) {
        const float xv = XA[ci * 68 + lane];
        const float* w3r = W3T + (unsigned)ci * 128u;
        #pragma unroll
        for (int c = 0; c < 32; ++c)
            aL[c] = fmaf(w3r[c], xv, aL[c]);
    }
    // mask channel: wave 3 only (wave-uniform branch), re-reads y2 from LDS
    float am = 0.0f;
    if (wv == 3) {
        for (int ci = 0; ci < 128; ++ci)
            am = fmaf(WM[ci], XA[ci * 68 + lane], am);
    }

    // per-wave argmax over its 32 couts (strict >, ascending index = numpy tie rule)
    {
        float m = aL[0] + b3f[wv * 32];
        int id = wv * 32;
        #pragma unroll
        for (int c = 1; c < 32; ++c) {
            float v = aL[c] + b3f[wv * 32 + c];
            if (v > m) { m = v; id = wv * 32 + c; }
        }
        rmax[wv * 68 + lane] = m;
        ridx[wv * 68 + lane] = id;
    }
    if (wv == 3)
        out_mask[nt + lane] = lrelu(am + b3f[128]);
    __syncthreads();
    if (t < 64) {
        float m = rmax[t];
        int id = ridx[t];
        #pragma unroll
        for (int w = 1; w < 4; ++w) {
            float v = rmax[w * 68 + t];
            if (v > m) { m = v; id = ridx[w * 68 + t]; }
        }
        inds[nt + t] = id;
        atomicAdd(&hist[id], 1);
    }
}

// exclusive scan of histogram + build tile work-queue (64 positions per tile)
__global__ void k_scan(const int* __restrict__ hist, int* __restrict__ off,
                       int* __restrict__ cur, int* __restrict__ tiles,
                       int* __restrict__ ntt)
{
    __shared__ int s[128];
    __shared__ int s2[128];
    int t = threadIdx.x;
    int v = hist[t];
    int ntk = (v + 63) >> 6;
    s[t] = v;
    s2[t] = ntk;
    __syncthreads();
    for (int d = 1; d < 128; d <<= 1) {
        int a  = (t >= d) ? s[t - d]  : 0;
        int a2 = (t >= d) ? s2[t - d] : 0;
        __syncthreads();
        s[t] += a;
        s2[t] += a2;
        __syncthreads();
    }
    off[t] = s[t] - v;
    cur[t] = s[t] - v;
    int tb = s2[t] - ntk;
    for (int j = 0; j < ntk; ++j)
        tiles[tb + j] = (t << 16) | j;
    if (t == 127) ntt[0] = s2[127];
}

// scatter positions into buckets, block-aggregated atomics
__global__ void k_scatter(const int* __restrict__ inds, int* __restrict__ cur,
                          int* __restrict__ bucket)
{
    __shared__ int lh[128];
    __shared__ int gb[128];
    int t = threadIdx.x;
    if (t < 128) lh[t] = 0;
    __syncthreads();
    int n = blockIdx.x * 256 + t;
    int id = inds[n];
    int r = atomicAdd(&lh[id], 1);          // LDS atomic: local rank
    __syncthreads();
    if (t < 128 && lh[t] > 0) gb[t] = atomicAdd(&cur[t], lh[t]);
    __syncthreads();
    bucket[gb[id] + r] = n;
}

// bucketed per-position MLP via tile work-queue; scalar weights via s_load.
// Block = 256 thr = 4 waves; tile = 64 positions; wave wv owns outs [wv*8, wv*8+8).
// x gathered position-minor into LDS [cin][68] (conflict-free).
__global__ __launch_bounds__(256, 4)
void k_reg(const float* __restrict__ XR, const float* __restrict__ cm2w,
           const float* __restrict__ cm2b, const float* __restrict__ cm3w,
           const float* __restrict__ cm3b, const int* __restrict__ hist,
           const int* __restrict__ off, const int* __restrict__ bucket,
           const int* __restrict__ tiles, const int* __restrict__ ntt,
           float* __restrict__ out)
{
    __shared__ float xP[128 * 68];
    __shared__ float red[4 * 68];
    int bid = blockIdx.x;
    if (bid >= ntt[0]) return;
    int desc = tiles[bid];                   // uniform load
    int k = desc >> 16;
    int start = (desc & 0xffff) << 6;
    int cnt = hist[k];
    int base = off[k];
    int t = threadIdx.x;
    int lane = t & 63;
    int wv = __builtin_amdgcn_readfirstlane(t >> 6);

    // gather 64 rows: lane = position, wave = 32-cin segment; transpose into LDS
    {
        int sidx = start + lane;
        if (sidx >= cnt) sidx = cnt - 1;     // clamp (output guarded below)
        int n = bucket[base + sidx];
        const float* src = XR + (unsigned)n * 128u + wv * 32;
        #pragma unroll
        for (int q = 0; q < 8; ++q) {
            float4 vq = *(const float4*)&src[q * 4];
            xP[(wv * 32 + q * 4 + 0) * 68 + lane] = vq.x;
            xP[(wv * 32 + q * 4 + 1) * 68 + lane] = vq.y;
            xP[(wv * 32 + q * 4 + 2) * 68 + lane] = vq.z;
            xP[(wv * 32 + q * 4 + 3) * 68 + lane] = vq.w;
        }
    }
    __syncthreads();

    const float* wk = cm2w + (unsigned)k * 4096u + wv * 8;   // [cin][32] rows
    float h[8] = {};
    for (int i = 0; i < 128; ++i) {
        float xv = xP[i * 68 + lane];
        const float* wr = wk + (unsigned)i * 32u;            // uniform -> s_load
        #pragma unroll
        for (int o = 0; o < 8; ++o)
            h[o] = fmaf(wr[o], xv, h[o]);
    }
    float partial = 0.0f;
    #pragma unroll
    for (int o = 0; o < 8; ++o) {
        float v = lrelu(h[o] + cm2b[k * 32 + wv * 8 + o]);
        partial = fmaf(v, cm3w[k * 32 + wv * 8 + o], partial);
    }
    red[wv * 68 + lane] = partial;
    __syncthreads();
    if (t < 64 && start + t < cnt) {
        float s = red[t] + red[68 + t] + red[136 + t] + red[204 + t] + cm3b[k];
        int n2 = bucket[base + start + t];
        out[n2] = ((float)k + s) * (1.0f / 128.0f);
    }
}

extern "C" void kernel_launch(void* const* d_in, const int* in_sizes, int n_in,
                              void* d_out, int out_size, void* d_ws, size_t ws_size,
                              hipStream_t stream)
{
    (void)in_sizes; (void)n_in; (void)out_size; (void)ws_size;
    const float* x_in   = (const float*)d_in[0];
    const float* cl1_w  = (const float*)d_in[1];
    const float* cl1_b  = (const float*)d_in[2];
    const float* g1     = (const float*)d_in[3];
    const float* be1    = (const float*)d_in[4];
    const float* mu1    = (const float*)d_in[5];
    const float* va1    = (const float*)d_in[6];
    const float* cl2_w  = (const float*)d_in[7];
    const float* cl2_b  = (const float*)d_in[8];
    const float* cl3_w  = (const float*)d_in[9];
    const float* cl3_b  = (const float*)d_in[10];
    const float* reg1_w = (const float*)d_in[11];
    const float* reg1_b = (const float*)d_in[12];
    const float* gr     = (const float*)d_in[13];
    const float* ber    = (const float*)d_in[14];
    const float* mur    = (const float*)d_in[15];
    const float* var_   = (const float*)d_in[16];
    const float* cm2w   = (const float*)d_in[17];
    const float* cm2b   = (const float*)d_in[18];
    const float* cm3w   = (const float*)d_in[19];
    const float* cm3b   = (const float*)d_in[20];

    float* ws_f = (float*)d_ws;
    float* XR   = ws_f + OFF_XR;
    int*   wsi    = (int*)(ws_f + OFF_INT);
    int*   inds   = wsi;
    int*   hist   = wsi + 65536;
    int*   offb   = hist + 128;
    int*   cur    = offb + 128;
    int*   ntt    = cur + 128;
    int*   tiles  = ntt + 4;
    int*   bucket = tiles + 1536;
    float* out = (float*)d_out;

    hipLaunchKernelGGL(k_prep, dim3(128), dim3(128), 0, stream,
                       cl1_w, cl1_b, g1, be1, mu1, va1, cl2_w, cl2_b, cl3_w, cl3_b,
                       reg1_w, reg1_b, gr, ber, mur, var_, ws_f, hist);
    hipLaunchKernelGGL(k_fused, dim3(1024), dim3(256), 0, stream,
                       x_in, ws_f, XR, out + 65536, inds, hist);
    hipLaunchKernelGGL(k_scan, dim3(1), dim3(128), 0, stream,
                       hist, offb, cur, tiles, ntt);
    hipLaunchKernelGGL(k_scatter, dim3(256), dim3(256), 0, stream, inds, cur, bucket);
    hipLaunchKernelGGL(k_reg, dim3(1536), dim3(256), 0, stream,
                       XR, cm2w, cm2b, cm3w, cm3b, hist, offb, bucket, tiles, ntt, out);
}

// Round 5
// 290.723 us; speedup vs baseline: 1.7613x; 1.2731x over previous
//
#include <hip/hip_runtime.h>
#include <math.h>

// Problem constants
#define NPOS 65536   // B*H*W = 8*1*8192
#define NCH  128
#define DELTA 0.008f // argmax top-2 gap below which we recompute in exact fp32

// ws layout (float element offsets)
#define OFF_XR   0u                       // xr [n][c] fp32 : 8388608 floats
#define OFF_W1T  8388608u                 // folded W1^T [cin][cout] fp32 (fixup)
#define OFF_WRT  (OFF_W1T + 16384u)
#define OFF_W2T  (OFF_WRT + 16384u)
#define OFF_W3T  (OFF_W2T + 16384u)
#define OFF_WM   (OFF_W3T + 16384u)
#define OFF_B1F  (OFF_WM + 128u)
#define OFF_BRF  (OFF_B1F + 128u)
#define OFF_B2F  (OFF_BRF + 128u)
#define OFF_B3F  (OFF_B2F + 128u)         // 132 (129 used)
#define OFF_BF16 (OFF_B3F + 132u)         // bf16 planes region (ushort*), 135168 ushorts
#define OFF_INT  (OFF_BF16 + 67584u)      // int region

// bf16 plane offsets (ushort units), [cout][cin] cin-contiguous
#define UW1H 0u
#define UW1L 16384u
#define UWRH 32768u
#define UWRL 49152u
#define UW2H 65536u
#define UW2L 81920u
#define UW3H 98304u      // [144][128]; row128=mask, rows129..143=0
#define UW3L 116736u

typedef short bf16x8 __attribute__((ext_vector_type(8)));
typedef float f32x4 __attribute__((ext_vector_type(4)));
#define MFMA16 __builtin_amdgcn_mfma_f32_16x16x32_bf16

__device__ __forceinline__ float lrelu(float v) { return v >= 0.0f ? v : 0.01f * v; }
__device__ __forceinline__ unsigned short f2bf(float f) {
    unsigned u = __float_as_uint(f);
    return (unsigned short)((u + 0x7fffu + ((u >> 16) & 1u)) >> 16);
}
__device__ __forceinline__ float bf2f(unsigned short h) {
    return __uint_as_float(((unsigned)h) << 16);
}

// ---------------------------------------------------------------------------
// prep: fold BN, fp32 transposed copies (for fixup), bf16 hi/lo planes (MFMA),
// zero hist + fixcnt
// ---------------------------------------------------------------------------
__global__ void k_prep(const float* __restrict__ cl1_w, const float* __restrict__ cl1_b,
                       const float* __restrict__ g1, const float* __restrict__ be1,
                       const float* __restrict__ mu1, const float* __restrict__ va1,
                       const float* __restrict__ cl2_w, const float* __restrict__ cl2_b,
                       const float* __restrict__ cl3_w, const float* __restrict__ cl3_b,
                       const float* __restrict__ reg1_w, const float* __restrict__ reg1_b,
                       const float* __restrict__ gr, const float* __restrict__ ber,
                       const float* __restrict__ mur, const float* __restrict__ var_,
                       float* __restrict__ ws_f, unsigned short* __restrict__ wbf,
                       int* __restrict__ hist, int* __restrict__ fixcnt)
{
    int tid = blockIdx.x * 128 + threadIdx.x;   // 16384 threads
    int cin = tid >> 7, cout = tid & 127;
    float s1 = g1[cout] / sqrtf(va1[cout] + 1e-5f);
    float sr = gr[cout] / sqrtf(var_[cout] + 1e-5f);
    float w1 = cl1_w[cout * 128 + cin] * s1;
    float wr = reg1_w[cout * 128 + cin] * sr;
    float w2 = cl2_w[cout * 128 + cin];
    float w3 = cl3_w[cout * 128 + cin];
    // fp32 [cin][cout] for fixup
    ws_f[OFF_W1T + tid] = w1;
    ws_f[OFF_WRT + tid] = wr;
    ws_f[OFF_W2T + tid] = w2;
    ws_f[OFF_W3T + tid] = w3;
    // bf16 hi/lo planes [cout][cin]
    int j = cout * 128 + cin;
    unsigned short h;
    h = f2bf(w1); wbf[UW1H + j] = h; wbf[UW1L + j] = f2bf(w1 - bf2f(h));
    h = f2bf(wr); wbf[UWRH + j] = h; wbf[UWRL + j] = f2bf(wr - bf2f(h));
    h = f2bf(w2); wbf[UW2H + j] = h; wbf[UW2L + j] = f2bf(w2 - bf2f(h));
    h = f2bf(w3); wbf[UW3H + j] = h; wbf[UW3L + j] = f2bf(w3 - bf2f(h));
    if (tid < 2048) {               // W3 rows 128..143: mask row then zeros
        int r = tid >> 7, ci = tid & 127;
        float v = (r == 0) ? cl3_w[128 * 128 + ci] : 0.0f;
        int jj = (128 + r) * 128 + ci;
        h = f2bf(v); wbf[UW3H + jj] = h; wbf[UW3L + jj] = f2bf(v - bf2f(h));
    }
    if (tid < 128) {
        float s1b = g1[tid] / sqrtf(va1[tid] + 1e-5f);
        float srb = gr[tid] / sqrtf(var_[tid] + 1e-5f);
        ws_f[OFF_WM  + tid] = cl3_w[128 * 128 + tid];
        ws_f[OFF_B1F + tid] = cl1_b[tid] * s1b + be1[tid] - mu1[tid] * s1b;
        ws_f[OFF_BRF + tid] = reg1_b[tid] * srb + ber[tid] - mur[tid] * srb;
        ws_f[OFF_B2F + tid] = cl2_b[tid];
        hist[tid] = 0;
    }
    if (tid < 129) ws_f[OFF_B3F + tid] = cl3_b[tid];
    if (tid == 0) fixcnt[0] = 0;
}

// ---------------------------------------------------------------------------
// FUSED pipeline on MFMA (bf16x3 split for ~fp32 precision).
// Block = 256 thr = 4 waves; tile = 64 pos x 128 cout; wave wv: couts [wv*32,+32).
// x/y tiles in LDS as bf16 hi/lo planes [pos][cin], stride 136 (2-way, free).
// Weights read as A-frags directly from global bf16 planes (L2-resident).
// P3 tracks top-2 logits; gap < DELTA -> fixup list (exact fp32 recompute).
// ---------------------------------------------------------------------------
__global__ __launch_bounds__(256, 2)
void k_fused(const float* __restrict__ X, const float* __restrict__ wsf,
             const unsigned short* __restrict__ wbf,
             float* __restrict__ XR, float* __restrict__ out_mask,
             int* __restrict__ inds, int* __restrict__ fixcnt,
             int* __restrict__ fixlist)
{
    __shared__ __align__(16) unsigned short XBh[64 * 136];
    __shared__ __align__(16) unsigned short XBl[64 * 136];
    __shared__ float sm1[4 * 64];
    __shared__ float sm2[4 * 64];
    __shared__ int   si1[4 * 64];

    const int t = threadIdx.x;
    const int lane = t & 63;
    const int cl16 = lane & 15;           // col / n within fragment
    const int q8 = (lane >> 4) * 8;       // k-offset within fragment
    const int q4 = (lane >> 4) * 4;       // row-offset within D fragment
    const int wv = __builtin_amdgcn_readfirstlane(t >> 6);
    const unsigned nt64 = blockIdx.x * 64u;
    const unsigned base = nt64 + (nt64 >> 13) * 1040384u;   // b*1048576 + w0

    const unsigned short* W1H = wbf + UW1H; const unsigned short* W1L = wbf + UW1L;
    const unsigned short* WRH = wbf + UWRH; const unsigned short* WRL = wbf + UWRL;
    const unsigned short* W2H = wbf + UW2H; const unsigned short* W2L = wbf + UW2L;
    const unsigned short* W3H = wbf + UW3H; const unsigned short* W3L = wbf + UW3L;
    const float* b1f = wsf + OFF_B1F;
    const float* brf = wsf + OFF_BRF;
    const float* b2f = wsf + OFF_B2F;
    const float* b3f = wsf + OFF_B3F;

    const f32x4 vzero = {0.f, 0.f, 0.f, 0.f};

    // ---- stage x tile -> bf16 hi/lo planes [pos][cin] ----
    {
        const int pos = t & 63, cig = t >> 6;      // cig: 0..3
        #pragma unroll
        for (int l = 0; l < 8; ++l) {
            int ci0 = cig * 32 + l * 4;
            float v0 = X[base + (unsigned)(ci0 + 0) * 8192u + pos];
            float v1 = X[base + (unsigned)(ci0 + 1) * 8192u + pos];
            float v2 = X[base + (unsigned)(ci0 + 2) * 8192u + pos];
            float v3 = X[base + (unsigned)(ci0 + 3) * 8192u + pos];
            unsigned short h0 = f2bf(v0), h1 = f2bf(v1), h2 = f2bf(v2), h3 = f2bf(v3);
            unsigned long long ph = (unsigned long long)h0 | ((unsigned long long)h1 << 16)
                                  | ((unsigned long long)h2 << 32) | ((unsigned long long)h3 << 48);
            unsigned short l0 = f2bf(v0 - bf2f(h0)), l1 = f2bf(v1 - bf2f(h1));
            unsigned short l2 = f2bf(v2 - bf2f(h2)), l3 = f2bf(v3 - bf2f(h3));
            unsigned long long pl = (unsigned long long)l0 | ((unsigned long long)l1 << 16)
                                  | ((unsigned long long)l2 << 32) | ((unsigned long long)l3 << 48);
            *(unsigned long long*)&XBh[pos * 136 + ci0] = ph;
            *(unsigned long long*)&XBl[pos * 136 + ci0] = pl;
        }
    }
    __syncthreads();

    // ---- P1: y1 (W1) and xr (WR) in one pass over B frags ----
    f32x4 aY[2][4], aR[2][4];
    #pragma unroll
    for (int m = 0; m < 2; ++m)
        #pragma unroll
        for (int n = 0; n < 4; ++n) { aY[m][n] = vzero; aR[m][n] = vzero; }
    #pragma unroll
    for (int kt = 0; kt < 4; ++kt) {
        bf16x8 Bh[4], Bl[4];
        #pragma unroll
        for (int n = 0; n < 4; ++n) {
            int bo = (n * 16 + cl16) * 136 + kt * 32 + q8;
            Bh[n] = *(const bf16x8*)&XBh[bo];
            Bl[n] = *(const bf16x8*)&XBl[bo];
        }
        #pragma unroll
        for (int m = 0; m < 2; ++m) {
            int ao = (wv * 32 + m * 16 + cl16) * 128 + kt * 32 + q8;
            bf16x8 a1h = *(const bf16x8*)&W1H[ao], a1l = *(const bf16x8*)&W1L[ao];
            bf16x8 arh = *(const bf16x8*)&WRH[ao], arl = *(const bf16x8*)&WRL[ao];
            #pragma unroll
            for (int n = 0; n < 4; ++n) {
                aY[m][n] = MFMA16(a1h, Bl[n], aY[m][n], 0, 0, 0);
                aY[m][n] = MFMA16(a1l, Bh[n], aY[m][n], 0, 0, 0);
                aY[m][n] = MFMA16(a1h, Bh[n], aY[m][n], 0, 0, 0);
                aR[m][n] = MFMA16(arh, Bl[n], aR[m][n], 0, 0, 0);
                aR[m][n] = MFMA16(arl, Bh[n], aR[m][n], 0, 0, 0);
                aR[m][n] = MFMA16(arh, Bh[n], aR[m][n], 0, 0, 0);
            }
        }
    }
    __syncthreads();                       // all P1 reads of XB done

    // xr epilogue -> global XR[n][c] fp32 (L2 write-combines the scatter)
    {
        #pragma unroll
        for (int m = 0; m < 2; ++m) {
            int cb = wv * 32 + m * 16 + q4;
            float br0 = brf[cb], br1 = brf[cb + 1], br2 = brf[cb + 2], br3 = brf[cb + 3];
            #pragma unroll
            for (int n = 0; n < 4; ++n) {
                unsigned pb = (nt64 + n * 16 + cl16) * 128u + cb;
                XR[pb]     = lrelu(aR[m][n][0] + br0);
                XR[pb + 1] = lrelu(aR[m][n][1] + br1);
                XR[pb + 2] = lrelu(aR[m][n][2] + br2);
                XR[pb + 3] = lrelu(aR[m][n][3] + br3);
            }
        }
    }
    // y1 epilogue -> XB planes
    {
        #pragma unroll
        for (int m = 0; m < 2; ++m) {
            int cb = wv * 32 + m * 16 + q4;
            float b0 = b1f[cb], b1 = b1f[cb + 1], b2 = b1f[cb + 2], b3 = b1f[cb + 3];
            #pragma unroll
            for (int n = 0; n < 4; ++n) {
                float v0 = lrelu(aY[m][n][0] + b0), v1 = lrelu(aY[m][n][1] + b1);
                float v2 = lrelu(aY[m][n][2] + b2), v3 = lrelu(aY[m][n][3] + b3);
                unsigned short h0 = f2bf(v0), h1 = f2bf(v1), h2 = f2bf(v2), h3 = f2bf(v3);
                unsigned long long ph = (unsigned long long)h0 | ((unsigned long long)h1 << 16)
                                      | ((unsigned long long)h2 << 32) | ((unsigned long long)h3 << 48);
                unsigned short l0 = f2bf(v0 - bf2f(h0)), l1 = f2bf(v1 - bf2f(h1));
                unsigned short l2 = f2bf(v2 - bf2f(h2)), l3 = f2bf(v3 - bf2f(h3));
                unsigned long long pl = (unsigned long long)l0 | ((unsigned long long)l1 << 16)
                                      | ((unsigned long long)l2 << 32) | ((unsigned long long)l3 << 48);
                int idx = (n * 16 + cl16) * 136 + cb;
                *(unsigned long long*)&XBh[idx] = ph;
                *(unsigned long long*)&XBl[idx] = pl;
            }
        }
    }
    __syncthreads();

    // ---- P2: y2 = lrelu(W2 y1 + b2) ----
    f32x4 aZ[2][4];
    #pragma unroll
    for (int m = 0; m < 2; ++m)
        #pragma unroll
        for (int n = 0; n < 4; ++n) aZ[m][n] = vzero;
    #pragma unroll
    for (int kt = 0; kt < 4; ++kt) {
        bf16x8 Bh[4], Bl[4];
        #pragma unroll
        for (int n = 0; n < 4; ++n) {
            int bo = (n * 16 + cl16) * 136 + kt * 32 + q8;
            Bh[n] = *(const bf16x8*)&XBh[bo];
            Bl[n] = *(const bf16x8*)&XBl[bo];
        }
        #pragma unroll
        for (int m = 0; m < 2; ++m) {
            int ao = (wv * 32 + m * 16 + cl16) * 128 + kt * 32 + q8;
            bf16x8 ah = *(const bf16x8*)&W2H[ao], al = *(const bf16x8*)&W2L[ao];
            #pragma unroll
            for (int n = 0; n < 4; ++n) {
                aZ[m][n] = MFMA16(ah, Bl[n], aZ[m][n], 0, 0, 0);
                aZ[m][n] = MFMA16(al, Bh[n], aZ[m][n], 0, 0, 0);
                aZ[m][n] = MFMA16(ah, Bh[n], aZ[m][n], 0, 0, 0);
            }
        }
    }
    __syncthreads();
    {
        #pragma unroll
        for (int m = 0; m < 2; ++m) {
            int cb = wv * 32 + m * 16 + q4;
            float b0 = b2f[cb], b1 = b2f[cb + 1], b2 = b2f[cb + 2], b3 = b2f[cb + 3];
            #pragma unroll
            for (int n = 0; n < 4; ++n) {
                float v0 = lrelu(aZ[m][n][0] + b0), v1 = lrelu(aZ[m][n][1] + b1);
                float v2 = lrelu(aZ[m][n][2] + b2), v3 = lrelu(aZ[m][n][3] + b3);
                unsigned short h0 = f2bf(v0), h1 = f2bf(v1), h2 = f2bf(v2), h3 = f2bf(v3);
                unsigned long long ph = (unsigned long long)h0 | ((unsigned long long)h1 << 16)
                                      | ((unsigned long long)h2 << 32) | ((unsigned long long)h3 << 48);
                unsigned short l0 = f2bf(v0 - bf2f(h0)), l1 = f2bf(v1 - bf2f(h1));
                unsigned short l2 = f2bf(v2 - bf2f(h2)), l3 = f2bf(v3 - bf2f(h3));
                unsigned long long pl = (unsigned long long)l0 | ((unsigned long long)l1 << 16)
                                      | ((unsigned long long)l2 << 32) | ((unsigned long long)l3 << 48);
                int idx = (n * 16 + cl16) * 136 + cb;
                *(unsigned long long*)&XBh[idx] = ph;
                *(unsigned long long*)&XBl[idx] = pl;
            }
        }
    }
    __syncthreads();

    // ---- P3: logits (+ mask row on wave 3) ----
    f32x4 aL[2][4], aM[4];
    #pragma unroll
    for (int m = 0; m < 2; ++m)
        #pragma unroll
        for (int n = 0; n < 4; ++n) aL[m][n] = vzero;
    #pragma unroll
    for (int n = 0; n < 4; ++n) aM[n] = vzero;
    #pragma unroll
    for (int kt = 0; kt < 4; ++kt) {
        bf16x8 Bh[4], Bl[4];
        #pragma unroll
        for (int n = 0; n < 4; ++n) {
            int bo = (n * 16 + cl16) * 136 + kt * 32 + q8;
            Bh[n] = *(const bf16x8*)&XBh[bo];
            Bl[n] = *(const bf16x8*)&XBl[bo];
        }
        #pragma unroll
        for (int m = 0; m < 2; ++m) {
            int ao = (wv * 32 + m * 16 + cl16) * 128 + kt * 32 + q8;
            bf16x8 ah = *(const bf16x8*)&W3H[ao], al = *(const bf16x8*)&W3L[ao];
            #pragma unroll
            for (int n = 0; n < 4; ++n) {
                aL[m][n] = MFMA16(ah, Bl[n], aL[m][n], 0, 0, 0);
                aL[m][n] = MFMA16(al, Bh[n], aL[m][n], 0, 0, 0);
                aL[m][n] = MFMA16(ah, Bh[n], aL[m][n], 0, 0, 0);
            }
        }
        if (wv == 3) {   // mask row block (rows 128..143, only row 128 used)
            int ao = (128 + cl16) * 128 + kt * 32 + q8;
            bf16x8 ah = *(const bf16x8*)&W3H[ao], al = *(const bf16x8*)&W3L[ao];
            #pragma unroll
            for (int n = 0; n < 4; ++n) {
                aM[n] = MFMA16(ah, Bl[n], aM[n], 0, 0, 0);
                aM[n] = MFMA16(al, Bh[n], aM[n], 0, 0, 0);
                aM[n] = MFMA16(ah, Bh[n], aM[n], 0, 0, 0);
            }
        }
    }

    // per-lane top-2 over its 8 couts (ascending cout = numpy first-tie rule)
    {
        float bb[2][4];
        #pragma unroll
        for (int m = 0; m < 2; ++m) {
            int cb = wv * 32 + m * 16 + q4;
            bb[m][0] = b3f[cb]; bb[m][1] = b3f[cb + 1];
            bb[m][2] = b3f[cb + 2]; bb[m][3] = b3f[cb + 3];
        }
        float m1[4], m2[4]; int i1[4];
        #pragma unroll
        for (int n = 0; n < 4; ++n) {
            m1[n] = -1e30f; m2[n] = -1e30f; i1[n] = 0;
            #pragma unroll
            for (int m = 0; m < 2; ++m) {
                int cb = wv * 32 + m * 16 + q4;
                #pragma unroll
                for (int r = 0; r < 4; ++r) {
                    float v = aL[m][n][r] + bb[m][r];
                    if (v > m1[n]) { m2[n] = m1[n]; m1[n] = v; i1[n] = cb + r; }
                    else if (v > m2[n]) m2[n] = v;
                }
            }
        }
        // merge across lane groups (same pos lives in lanes cl16+16g)
        #pragma unroll
        for (int off = 16; off <= 32; off <<= 1) {
            #pragma unroll
            for (int n = 0; n < 4; ++n) {
                float om1 = __shfl_xor(m1[n], off);
                float om2 = __shfl_xor(m2[n], off);
                int   oi1 = __shfl_xor(i1[n], off);
                if (om1 > m1[n] || (om1 == m1[n] && oi1 < i1[n])) {
                    m2[n] = fmaxf(m1[n], om2); m1[n] = om1; i1[n] = oi1;
                } else {
                    m2[n] = fmaxf(m2[n], om1);
                }
            }
        }
        if ((lane >> 4) == 0) {
            #pragma unroll
            for (int n = 0; n < 4; ++n) {
                sm1[wv * 64 + n * 16 + cl16] = m1[n];
                sm2[wv * 64 + n * 16 + cl16] = m2[n];
                si1[wv * 64 + n * 16 + cl16] = i1[n];
            }
        }
    }
    if (wv == 3 && (lane >> 4) == 0) {
        float mb = b3f[128];
        #pragma unroll
        for (int n = 0; n < 4; ++n)
            out_mask[nt64 + n * 16 + cl16] = lrelu(aM[n][0] + mb);
    }
    __syncthreads();
    if (t < 64) {
        float m1 = sm1[t], m2 = sm2[t];
        int i1 = si1[t];
        #pragma unroll
        for (int w = 1; w < 4; ++w) {     // ascending wv = ascending cout
            float v1 = sm1[w * 64 + t];
            float v2 = sm2[w * 64 + t];
            int   vi = si1[w * 64 + t];
            if (v1 > m1) { m2 = fmaxf(m1, v2); m1 = v1; i1 = vi; }
            else         { m2 = fmaxf(m2, v1); }
        }
        int n = nt64 + t;
        inds[n] = i1;
        if (m1 - m2 < DELTA) {
            int slot = atomicAdd(fixcnt, 1);
            fixlist[slot] = n;
        }
    }
}

// ---------------------------------------------------------------------------
// fixup: exact fp32 recompute of logits+argmax for flagged positions
// (scalar-weight chain; grid sized for worst case, blocks with no work exit)
// ---------------------------------------------------------------------------
__global__ __launch_bounds__(256, 4)
void k_fix(const float* __restrict__ X, const float* __restrict__ wsf,
           const int* __restrict__ fixcnt, const int* __restrict__ fixlist,
           int* __restrict__ inds)
{
    __shared__ float XA[128 * 68];
    __shared__ float rmax[4 * 68];
    __shared__ int   ridx[4 * 68];
    int cnt = fixcnt[0];
    int start = blockIdx.x * 64;
    if (start >= cnt) return;
    int t = threadIdx.x;
    int lane = t & 63;
    int wv = __builtin_amdgcn_readfirstlane(t >> 6);

    const float* W1T = wsf + OFF_W1T + wv * 32;
    const float* W2T = wsf + OFF_W2T + wv * 32;
    const float* W3T = wsf + OFF_W3T + wv * 32;
    const float* b1f = wsf + OFF_B1F + wv * 32;
    const float* b2f = wsf + OFF_B2F + wv * 32;
    const float* b3f = wsf + OFF_B3F;

    // gather x columns for up to 64 flagged positions
    {
        int idx = start + lane;
        if (idx >= cnt) idx = cnt - 1;
        int n = fixlist[idx];
        unsigned g0 = (unsigned)(n >> 13) * 1048576u + (unsigned)(n & 8191);
        int seg = t >> 6;
        for (int l = 0; l < 32; ++l) {
            int ci = seg * 32 + l;
            XA[ci * 68 + lane] = X[g0 + (unsigned)ci * 8192u];
        }
    }
    __syncthreads();

    float aY[32] = {};
    for (int ci = 0; ci < 128; ++ci) {
        const float xv = XA[ci * 68 + lane];
        const float* w1r = W1T + (unsigned)ci * 128u;
        #pragma unroll
        for (int c = 0; c < 32; ++c) aY[c] = fmaf(w1r[c], xv, aY[c]);
    }
    __syncthreads();
    #pragma unroll
    for (int c = 0; c < 32; ++c)
        XA[(wv * 32 + c) * 68 + lane] = lrelu(aY[c] + b1f[c]);
    __syncthreads();

    float aZ[32] = {};
    for (int ci = 0; ci < 128; ++ci) {
        const float xv = XA[ci * 68 + lane];
        const float* w2r = W2T + (unsigned)ci * 128u;
        #pragma unroll
        for (int c = 0; c < 32; ++c) aZ[c] = fmaf(w2r[c], xv, aZ[c]);
    }
    __syncthreads();
    #pragma unroll
    for (int c = 0; c < 32; ++c)
        XA[(wv * 32 + c) * 68 + lane] = lrelu(aZ[c] + b2f[c]);
    __syncthreads();

    float aL[32] = {};
    for (int ci = 0; ci < 128; ++ci) {
        const float xv = XA[ci * 68 + lane];
        const float* w3r = W3T + (unsigned)ci * 128u;
        #pragma unroll
        for (int c = 0; c < 32; ++c) aL[c] = fmaf(w3r[c], xv, aL[c]);
    }
    {
        float m = aL[0] + b3f[wv * 32];
        int id = wv * 32;
        #pragma unroll
        for (int c = 1; c < 32; ++c) {
            float v = aL[c] + b3f[wv * 32 + c];
            if (v > m) { m = v; id = wv * 32 + c; }
        }
        rmax[wv * 68 + lane] = m;
        ridx[wv * 68 + lane] = id;
    }
    __syncthreads();
    if (t < 64 && start + t < cnt) {
        float m = rmax[t];
        int id = ridx[t];
        #pragma unroll
        for (int w = 1; w < 4; ++w) {
            float v = rmax[w * 68 + t];
            if (v > m) { m = v; id = ridx[w * 68 + t]; }
        }
        inds[fixlist[start + t]] = id;
    }
}

// histogram from final inds (block-aggregated atomics)
__global__ void k_hist(const int* __restrict__ inds, int* __restrict__ hist)
{
    __shared__ int lh[128];
    int t = threadIdx.x;
    if (t < 128) lh[t] = 0;
    __syncthreads();
    atomicAdd(&lh[inds[blockIdx.x * 256 + t]], 1);
    __syncthreads();
    if (t < 128 && lh[t] > 0) atomicAdd(&hist[t], lh[t]);
}

// exclusive scan of histogram + build tile work-queue (64 positions per tile)
__global__ void k_scan(const int* __restrict__ hist, int* __restrict__ off,
                       int* __restrict__ cur, int* __restrict__ tiles,
                       int* __restrict__ ntt)
{
    __shared__ int s[128];
    __shared__ int s2[128];
    int t = threadIdx.x;
    int v = hist[t];
    int ntk = (v + 63) >> 6;
    s[t] = v;
    s2[t] = ntk;
    __syncthreads();
    for (int d = 1; d < 128; d <<= 1) {
        int a  = (t >= d) ? s[t - d]  : 0;
        int a2 = (t >= d) ? s2[t - d] : 0;
        __syncthreads();
        s[t] += a;
        s2[t] += a2;
        __syncthreads();
    }
    off[t] = s[t] - v;
    cur[t] = s[t] - v;
    int tb = s2[t] - ntk;
    for (int j = 0; j < ntk; ++j)
        tiles[tb + j] = (t << 16) | j;
    if (t == 127) ntt[0] = s2[127];
}

// scatter positions into buckets, block-aggregated atomics
__global__ void k_scatter(const int* __restrict__ inds, int* __restrict__ cur,
                          int* __restrict__ bucket)
{
    __shared__ int lh[128];
    __shared__ int gb[128];
    int t = threadIdx.x;
    if (t < 128) lh[t] = 0;
    __syncthreads();
    int n = blockIdx.x * 256 + t;
    int id = inds[n];
    int r = atomicAdd(&lh[id], 1);
    __syncthreads();
    if (t < 128 && lh[t] > 0) gb[t] = atomicAdd(&cur[t], lh[t]);
    __syncthreads();
    bucket[gb[id] + r] = n;
}

// bucketed per-position MLP via tile work-queue; scalar weights via s_load.
__global__ __launch_bounds__(256, 4)
void k_reg(const float* __restrict__ XR, const float* __restrict__ cm2w,
           const float* __restrict__ cm2b, const float* __restrict__ cm3w,
           const float* __restrict__ cm3b, const int* __restrict__ hist,
           const int* __restrict__ off, const int* __restrict__ bucket,
           const int* __restrict__ tiles, const int* __restrict__ ntt,
           float* __restrict__ out)
{
    __shared__ float xP[128 * 68];
    __shared__ float red[4 * 68];
    int bid = blockIdx.x;
    if (bid >= ntt[0]) return;
    int desc = tiles[bid];
    int k = desc >> 16;
    int start = (desc & 0xffff) << 6;
    int cnt = hist[k];
    int base = off[k];
    int t = threadIdx.x;
    int lane = t & 63;
    int wv = __builtin_amdgcn_readfirstlane(t >> 6);

    {
        int sidx = start + lane;
        if (sidx >= cnt) sidx = cnt - 1;
        int n = bucket[base + sidx];
        const float* src = XR + (unsigned)n * 128u + wv * 32;
        #pragma unroll
        for (int q = 0; q < 8; ++q) {
            float4 vq = *(const float4*)&src[q * 4];
            xP[(wv * 32 + q * 4 + 0) * 68 + lane] = vq.x;
            xP[(wv * 32 + q * 4 + 1) * 68 + lane] = vq.y;
            xP[(wv * 32 + q * 4 + 2) * 68 + lane] = vq.z;
            xP[(wv * 32 + q * 4 + 3) * 68 + lane] = vq.w;
        }
    }
    __syncthreads();

    const float* wk = cm2w + (unsigned)k * 4096u + wv * 8;
    float h[8] = {};
    for (int i = 0; i < 128; ++i) {
        float xv = xP[i * 68 + lane];
        const float* wr = wk + (unsigned)i * 32u;
        #pragma unroll
        for (int o = 0; o < 8; ++o)
            h[o] = fmaf(wr[o], xv, h[o]);
    }
    float partial = 0.0f;
    #pragma unroll
    for (int o = 0; o < 8; ++o) {
        float v = lrelu(h[o] + cm2b[k * 32 + wv * 8 + o]);
        partial = fmaf(v, cm3w[k * 32 + wv * 8 + o], partial);
    }
    red[wv * 68 + lane] = partial;
    __syncthreads();
    if (t < 64 && start + t < cnt) {
        float s = red[t] + red[68 + t] + red[136 + t] + red[204 + t] + cm3b[k];
        int n2 = bucket[base + start + t];
        out[n2] = ((float)k + s) * (1.0f / 128.0f);
    }
}

extern "C" void kernel_launch(void* const* d_in, const int* in_sizes, int n_in,
                              void* d_out, int out_size, void* d_ws, size_t ws_size,
                              hipStream_t stream)
{
    (void)in_sizes; (void)n_in; (void)out_size; (void)ws_size;
    const float* x_in   = (const float*)d_in[0];
    const float* cl1_w  = (const float*)d_in[1];
    const float* cl1_b  = (const float*)d_in[2];
    const float* g1     = (const float*)d_in[3];
    const float* be1    = (const float*)d_in[4];
    const float* mu1    = (const float*)d_in[5];
    const float* va1    = (const float*)d_in[6];
    const float* cl2_w  = (const float*)d_in[7];
    const float* cl2_b  = (const float*)d_in[8];
    const float* cl3_w  = (const float*)d_in[9];
    const float* cl3_b  = (const float*)d_in[10];
    const float* reg1_w = (const float*)d_in[11];
    const float* reg1_b = (const float*)d_in[12];
    const float* gr     = (const float*)d_in[13];
    const float* ber    = (const float*)d_in[14];
    const float* mur    = (const float*)d_in[15];
    const float* var_   = (const float*)d_in[16];
    const float* cm2w   = (const float*)d_in[17];
    const float* cm2b   = (const float*)d_in[18];
    const float* cm3w   = (const float*)d_in[19];
    const float* cm3b   = (const float*)d_in[20];

    float* ws_f = (float*)d_ws;
    float* XR   = ws_f + OFF_XR;
    unsigned short* wbf = (unsigned short*)(ws_f + OFF_BF16);
    int*   wsi    = (int*)(ws_f + OFF_INT);
    int*   inds   = wsi;
    int*   hist   = inds + 65536;
    int*   offb   = hist + 128;
    int*   cur    = offb + 128;
    int*   ntt    = cur + 128;
    int*   fixcnt = ntt + 4;
    int*   tiles  = fixcnt + 4;
    int*   fixlist= tiles + 1536;
    int*   bucket = fixlist + 65536;
    float* out = (float*)d_out;

    hipLaunchKernelGGL(k_prep, dim3(128), dim3(128), 0, stream,
                       cl1_w, cl1_b, g1, be1, mu1, va1, cl2_w, cl2_b, cl3_w, cl3_b,
                       reg1_w, reg1_b, gr, ber, mur, var_, ws_f, wbf, hist, fixcnt);
    hipLaunchKernelGGL(k_fused, dim3(1024), dim3(256), 0, stream,
                       x_in, ws_f, wbf, XR, out + 65536, inds, fixcnt, fixlist);
    hipLaunchKernelGGL(k_fix, dim3(1024), dim3(256), 0, stream,
                       x_in, ws_f, fixcnt, fixlist, inds);
    hipLaunchKernelGGL(k_hist, dim3(256), dim3(256), 0, stream, inds, hist);
    hipLaunchKernelGGL(k_scan, dim3(1), dim3(128), 0, stream,
                       hist, offb, cur, tiles, ntt);
    hipLaunchKernelGGL(k_scatter, dim3(256), dim3(256), 0, stream, inds, cur, bucket);
    hipLaunchKernelGGL(k_reg, dim3(1536), dim3(256), 0, stream,
                       XR, cm2w, cm2b, cm3w, cm3b, hist, offb, bucket, tiles, ntt, out);
}